// Round 1
// baseline (74.581 us; speedup 1.0000x reference)
//
#include <hip/hip_runtime.h>
#include <math.h>

#define POOL 7
#define NUM_ROIS 300
#define FH 50
#define FW 50
#define FC 512

// Kernel 1: fmax[h][w] = max over C of feature_maps[h][w][c]
// One wave (64 lanes) per pixel. 512 floats = 128 float4; 2 float4/lane.
__global__ __launch_bounds__(64) void channel_max_kernel(
    const float* __restrict__ fm, float* __restrict__ fmax_g) {
    int pix = blockIdx.x;                       // 0..2499
    int lane = threadIdx.x;                     // 0..63
    const float4* p = (const float4*)(fm + (size_t)pix * FC);
    float4 a = p[lane];
    float4 b = p[lane + 64];
    float m = fmaxf(fmaxf(fmaxf(a.x, a.y), fmaxf(a.z, a.w)),
                    fmaxf(fmaxf(b.x, b.y), fmaxf(b.z, b.w)));
    #pragma unroll
    for (int off = 32; off > 0; off >>= 1)
        m = fmaxf(m, __shfl_down(m, off, 64));
    if (lane == 0) fmax_g[pix] = m;
}

// Kernel 2: one block per ROI. Compute 7x7 pooled maxes from the 50x50 fmax
// map (staged in LDS), then broadcast each bin value across 512 channels.
__global__ __launch_bounds__(256) void roi_pool_kernel(
    const float* __restrict__ rois, const float* __restrict__ fmax_g,
    float* __restrict__ out) {
    __shared__ float sfmax[FH * FW];     // 10 KB
    __shared__ float pooled[POOL * POOL];

    int n = blockIdx.x;
    for (int t = threadIdx.x; t < FH * FW; t += blockDim.x)
        sfmax[t] = fmax_g[t];

    // Replicate: r = int32(roi * (1/16))  (truncation; values non-negative)
    int x1 = (int)(rois[n * 5 + 1] * 0.0625f);
    int y1 = (int)(rois[n * 5 + 2] * 0.0625f);
    int x2 = (int)(rois[n * 5 + 3] * 0.0625f);
    int y2 = (int)(rois[n * 5 + 4] * 0.0625f);
    int rh = y2 - y1 + 1;
    int rw = x2 - x1 + 1;

    __syncthreads();

    if (threadIdx.x < POOL * POOL) {
        int i = threadIdx.x / POOL;   // row bin
        int j = threadIdx.x % POOL;   // col bin
        // Python floor-div on non-negative ints == C int division here.
        int hs = min(max(y1 + (i * rh) / POOL, 0), FH);
        int he = min(max(y1 + ((i + 1) * rh + POOL - 1) / POOL, 0), FH);
        int ws = min(max(x1 + (j * rw) / POOL, 0), FW);
        int we = min(max(x1 + ((j + 1) * rw + POOL - 1) / POOL, 0), FW);
        float m = -INFINITY;          // empty bin -> -inf, matching reference
        for (int h = hs; h < he; ++h)
            for (int w = ws; w < we; ++w)
                m = fmaxf(m, sfmax[h * FW + w]);
        pooled[threadIdx.x] = m;
    }
    __syncthreads();

    // Broadcast write: 49 bins x 512 ch = 49*128 float4 per ROI, coalesced.
    float4* o4 = (float4*)(out + (size_t)n * POOL * POOL * FC);
    const int total4 = POOL * POOL * (FC / 4);  // 6272
    for (int t = threadIdx.x; t < total4; t += blockDim.x) {
        float v = pooled[t >> 7];               // t / (512/4)
        o4[t] = make_float4(v, v, v, v);
    }
}

extern "C" void kernel_launch(void* const* d_in, const int* in_sizes, int n_in,
                              void* d_out, int out_size, void* d_ws, size_t ws_size,
                              hipStream_t stream) {
    const float* rois = (const float*)d_in[0];          // (300, 5) f32
    const float* feature_maps = (const float*)d_in[1];  // (50, 50, 512) f32
    float* out = (float*)d_out;                         // (300, 7, 7, 512) f32
    float* fmax_g = (float*)d_ws;                       // 2500 floats scratch

    channel_max_kernel<<<FH * FW, 64, 0, stream>>>(feature_maps, fmax_g);
    roi_pool_kernel<<<NUM_ROIS, 256, 0, stream>>>(rois, fmax_g, out);
}